// Round 1
// baseline (120.828 us; speedup 1.0000x reference)
//
#include <hip/hip_runtime.h>
#include <hip/hip_bf16.h>

#define NN_ 1024

// ws layout (~12.9 MB of 256 MiB ws)
#define U_WGF   0        // ushort idx: 131072  Wg fragment-major, quadrant-remapped
#define F_WOUT  65536    // float  idx (byte 262144): 16384 f32 WoutT[r][j], j>=120 zero
#define U_P     163840   // ushort idx (byte 327680): 4194304 P[m][g*64+e] bf16 (8 MB)
#define I_OFF   2179072  // uint   idx (byte 8716288): 1048576  per-agent neighbor offsets
#define I_CNT   3227648  // uint   idx: 1024 per-agent neighbor counts

typedef __attribute__((ext_vector_type(8))) short short8;
typedef __attribute__((ext_vector_type(4))) float floatx4;

// LDS A-tile byte offset with XOR swizzle (breaks the 512B-row-stride bank conflict
// on ds_read_b128: lanes m=0..15 reading column slices land on 8 distinct 16B slots)
#define AT(r,c) ((((r)<<9) + ((c)<<1)) ^ (((r)&7)<<4))

__device__ __forceinline__ float b2f_(unsigned short u) {
    return __uint_as_float(((unsigned)u) << 16);           // bf16 -> f32, exact
}
__device__ __forceinline__ unsigned short f2bu(float f) {  // f32 -> bf16 bits (RNE)
    __hip_bfloat16 b = __float2bfloat16(f);
    return *(unsigned short*)&b;
}
__device__ __forceinline__ float ldin(const void* p, int i, int isbf) {
    return isbf ? b2f_(((const unsigned short*)p)[i]) : ((const float*)p)[i];
}
__device__ __forceinline__ int detect_bf16(const void* Wih, int tid) {
    unsigned wv = ((const unsigned*)Wih)[tid];
    unsigned e8 = (wv >> 7) & 0xFFu;
    return (__syncthreads_count((e8 >= 96u && e8 <= 134u) ? 1 : 0) > 128) ? 1 : 0;
}
// load 8 consecutive input elements starting at element idx as bf16x8
__device__ __forceinline__ short8 ld8_bf(const void* p, int idx, int isbf) {
    if (isbf) return *(const short8*)((const unsigned short*)p + idx);
    const float4* f = (const float4*)((const float*)p + idx);
    float4 a = f[0], b = f[1];
    short8 r;
    r[0] = (short)f2bu(a.x); r[1] = (short)f2bu(a.y);
    r[2] = (short)f2bu(a.z); r[3] = (short)f2bu(a.w);
    r[4] = (short)f2bu(b.x); r[5] = (short)f2bu(b.y);
    r[6] = (short)f2bu(b.z); r[7] = (short)f2bu(b.w);
    return r;
}

// ---- Kernel A: P-GEMM (direct f32 loads) + neighbor detect + Wg remap + WoutT ----
// blocks [0,512): pgemm  M_b=32, N_b=256 (2048 waves = 2/SIMD)
// blocks [512,768): detect, 4 agents each -> OFF lists + CNT
// blocks [768,832): Wg fragment remap     blocks [832,840): WoutT
__global__ __launch_bounds__(256) void fused1_kernel(
        const void* __restrict__ xabs, const void* __restrict__ h0,
        const void* __restrict__ Wsoc, const void* __restrict__ Wih,
        const void* __restrict__ Whh,  const void* __restrict__ Wout,
        float* __restrict__ ws) {
    const int tid = threadIdx.x;
    const int bid = blockIdx.x;
    const int isbf = detect_bf16(Wih, tid);
    unsigned short* u = (unsigned short*)ws;

    if (bid < 512) {
        // P[m][col] = sum_k h0[m][k] * Wsoc[e][g*128+k],  col = g*64+e
        unsigned short* P16 = u + U_P;
        const int mg = bid >> 4, ng = bid & 15;
        const int lane = tid & 63, wv = tid >> 6;
        const int m = lane & 15, q = lane >> 4;
        short8 ah[2][4];
#pragma unroll
        for (int mt = 0; mt < 2; ++mt) {
            const int row = mg * 32 + mt * 16 + m;
#pragma unroll
            for (int kb = 0; kb < 4; ++kb)
                ah[mt][kb] = ld8_bf(h0, row * 128 + kb * 32 + q * 8, isbf);
        }
#pragma unroll
        for (int c = 0; c < 4; ++c) {
            const int ct = wv * 4 + c;
            const int col = ng * 256 + ct * 16 + m;
            const int g = col >> 6, e = col & 63;
            short8 bf[4];
#pragma unroll
            for (int kb = 0; kb < 4; ++kb)
                bf[kb] = ld8_bf(Wsoc, e * 8192 + g * 128 + kb * 32 + q * 8, isbf);
            floatx4 c0_ = {0.f, 0.f, 0.f, 0.f}, c1_ = {0.f, 0.f, 0.f, 0.f};
#pragma unroll
            for (int kb = 0; kb < 4; ++kb) {
                c0_ = __builtin_amdgcn_mfma_f32_16x16x32_bf16(ah[0][kb], bf[kb], c0_, 0, 0, 0);
                c1_ = __builtin_amdgcn_mfma_f32_16x16x32_bf16(ah[1][kb], bf[kb], c1_, 0, 0, 0);
            }
#pragma unroll
            for (int r = 0; r < 4; ++r) {          // D: col=lane&15, row=q*4+r
                P16[(mg * 32 + q * 4 + r) * 4096 + col]      = f2bu(c0_[r]);
                P16[(mg * 32 + 16 + q * 4 + r) * 4096 + col] = f2bu(c1_[r]);
            }
        }
    } else if (bid < 768) {
        // neighbor detection for agents n0..n0+3 -> OFF/CNT (overlaps pgemm)
        __shared__ float xs_[2048];
        __shared__ int cnt_s[4];
        for (int i = tid; i < 2048; i += 256) xs_[i] = ldin(xabs, i, isbf);
        if (tid < 4) cnt_s[tid] = 0;
        __syncthreads();
        const int a = tid >> 6, t = tid & 63;
        const int n = (bid - 512) * 4 + a;
        unsigned* OFF = (unsigned*)ws + I_OFF + n * 1024;
        const float xsn = xs_[2 * n]     - 0.2f;   // x[n] - NS/2
        const float ysn = xs_[2 * n + 1] - 0.2f;
        for (int i = t; i < NN_; i += 64) {
            float dx = xs_[2 * i]     - xsn;
            float dy = xs_[2 * i + 1] - ysn;
            int cx = (int)floorf(dx / 0.4f * 8.0f);
            int cy = (int)floorf(dy / 0.4f * 8.0f);
            bool valid = (dx >= 0.0f) && (dx < 0.4f) && (dy >= 0.0f) && (dy < 0.4f)
                      && (cx >= 0) && (cx < 8) && (cy >= 0) && (cy < 8) && (i != n);
            if (valid) {
                int pos = atomicAdd(&cnt_s[a], 1);
                OFF[pos] = (unsigned)(i * 4096 + ((cy * 8 + cx) << 6));
            }
        }
        __syncthreads();
        if (tid < 4) ((unsigned*)ws)[I_CNT + (bid - 512) * 4 + tid] = (unsigned)cnt_s[tid];
    } else if (bid < 832) {
        // Wg fragment-major, quadrant-remapped (same layout as prior kernel)
        const int t0 = (bid - 768) * 2048 + tid * 8;
        const int jl = (t0 >> 3) & 15, qq = (t0 >> 7) & 3, kb = (t0 >> 9) & 7, jt = t0 >> 12;
        const int j = (jt & 3) * 128 + (jt >> 2) * 16 + jl;
        const int k0 = kb * 32 + qq * 8;
        unsigned short hv[8];
#pragma unroll
        for (int r = 0; r < 8; ++r) {
            int k = k0 + r;
            float v = (k < 128) ? ldin(Wih, j * 128 + k, isbf)
                                : ldin(Whh, j * 128 + (k - 128), isbf);
            hv[r] = f2bu(v);
        }
        *(short8*)(u + U_WGF + t0) = *(short8*)hv;
    } else {
        // WoutT f32 [r][j]
        const int t2 = (bid - 832) * 2048 + tid * 8;
        const int r = t2 >> 7, j0 = t2 & 127;
#pragma unroll
        for (int i = 0; i < 8; ++i) {
            int j = j0 + i;
            ws[F_WOUT + t2 + i] = (j < 120) ? ldin(Wout, j * 128 + r, isbf) : 0.0f;
        }
    }
}

// ---- Kernel B: pool gather + emb + gates MFMA + LSTM + W_out, 4 agents/block ----
__global__ __launch_bounds__(256) void fused2_kernel(
        const void* __restrict__ xoff, const void* __restrict__ h0,
        const void* __restrict__ c0,   const void* __restrict__ Wemb,
        const void* __restrict__ bemb, const void* __restrict__ bsoc,
        const void* __restrict__ bih,  const void* __restrict__ bhh,
        const void* __restrict__ bout, const void* __restrict__ Wih_det,
        const float* __restrict__ ws,  float* __restrict__ out) {
    __shared__ __align__(16) unsigned short At[4096];   // 16x256 bf16, AT()-swizzled
    __shared__ float red[4][8][64];
    __shared__ float gl[4][512];
    __shared__ __align__(16) float hnl[4][128];
    const int tid = threadIdx.x;
    const int isbf = detect_bf16(Wih_det, tid);
    const int n0 = blockIdx.x * 4;
    char* atb = (char*)At;
    const unsigned short* P16 = (const unsigned short*)ws + U_P;

    {   // gather: per agent 8 streams x 8 e-lanes, 16B/lane, 4-deep unroll
        const int a = tid >> 6, s = (tid >> 3) & 7, l = tid & 7;
        const unsigned cnt = ((const unsigned*)ws)[I_CNT + n0 + a];
        const unsigned* lst = (const unsigned*)ws + I_OFF + (n0 + a) * 1024;
        float acc[8] = {0.f, 0.f, 0.f, 0.f, 0.f, 0.f, 0.f, 0.f};
        unsigned j = s;
        while (j + 24 < cnt) {
            unsigned o0 = lst[j], o1 = lst[j + 8], o2 = lst[j + 16], o3 = lst[j + 24];
            short8 v0 = *(const short8*)(P16 + o0 + l * 8);
            short8 v1 = *(const short8*)(P16 + o1 + l * 8);
            short8 v2 = *(const short8*)(P16 + o2 + l * 8);
            short8 v3 = *(const short8*)(P16 + o3 + l * 8);
#pragma unroll
            for (int i = 0; i < 8; ++i)
                acc[i] += b2f_((unsigned short)v0[i]) + b2f_((unsigned short)v1[i])
                        + b2f_((unsigned short)v2[i]) + b2f_((unsigned short)v3[i]);
            j += 32;
        }
        while (j < cnt) {
            unsigned o0 = lst[j];
            short8 v0 = *(const short8*)(P16 + o0 + l * 8);
#pragma unroll
            for (int i = 0; i < 8; ++i) acc[i] += b2f_((unsigned short)v0[i]);
            j += 8;
        }
#pragma unroll
        for (int i = 0; i < 8; ++i) red[a][s][l * 8 + i] = acc[i];
    }
    __syncthreads();
    {   // pool reduce -> A[k=64..127]; emb -> A[k=0..63]
        const int a = tid >> 6, e = tid & 63;
        float p = 0.f;
#pragma unroll
        for (int s = 0; s < 8; ++s) p += red[a][s][e];
        p += ldin(bsoc, e, isbf);
        *(unsigned short*)(atb + AT(a, 64 + e)) = f2bu(fmaxf(p, 0.0f));
        float x0 = ldin(xoff, 2 * (n0 + a), isbf), x1 = ldin(xoff, 2 * (n0 + a) + 1, isbf);
        float v = fmaf(x0, ldin(Wemb, 2 * e, isbf),
                  fmaf(x1, ldin(Wemb, 2 * e + 1, isbf), ldin(bemb, e, isbf)));
        *(unsigned short*)(atb + AT(a, e)) = f2bu(fmaxf(v, 0.0f));
    }
    for (int z = tid; z < 512; z += 256) {              // h0 -> A[k=128..255]
        int a = z >> 7, k = z & 127;
        *(unsigned short*)(atb + AT(a, 128 + k)) = f2bu(ldin(h0, (n0 + a) * 128 + k, isbf));
    }
    for (int z = tid; z < 3072; z += 256) {             // zero pad rows 4..15
        int row = 4 + (z >> 8), col = z & 255;
        *(unsigned short*)(atb + AT(row, col)) = 0;
    }
    __syncthreads();
    {   // gates: wave wv = quadrant (i/f/g/o), 8 j-tiles x 8 k-blocks
        const int lane = tid & 63, wv = tid >> 6, m = lane & 15, q = lane >> 4;
        short8 af[8];
#pragma unroll
        for (int kb = 0; kb < 8; ++kb)
            af[kb] = *(const short8*)(atb + AT(m, kb * 32 + q * 8));
        const short* Wg = (const short*)((const unsigned short*)ws + U_WGF);
#pragma unroll
        for (int y2 = 0; y2 < 8; ++y2) {
            floatx4 c = {0.f, 0.f, 0.f, 0.f};
#pragma unroll
            for (int kb = 0; kb < 8; ++kb) {
                short8 b = *(const short8*)(Wg + ((y2 * 4 + wv) * 8 + kb) * 512 + q * 128 + m * 8);
                c = __builtin_amdgcn_mfma_f32_16x16x32_bf16(af[kb], b, c, 0, 0, 0);
            }
            if (q == 0) {                               // D rows 0..3 = our 4 agents
                const int jor = wv * 128 + y2 * 16 + m;
                const float bias = ldin(bih, jor, isbf) + ldin(bhh, jor, isbf);
#pragma unroll
                for (int r = 0; r < 4; ++r)
                    gl[r][wv * 128 + y2 * 16 + m] = c[r] + bias;
            }
        }
    }
    __syncthreads();
    for (int z = tid; z < 512; z += 256) {              // LSTM pointwise -> hnl
        const int a = z >> 7, r = z & 127, n = n0 + a;
        float iv = gl[a][r],       fv = gl[a][128 + r];
        float gv = gl[a][256 + r], ov = gl[a][384 + r];
        float si = 1.0f / (1.0f + expf(-iv));
        float sf = 1.0f / (1.0f + expf(-fv));
        float so = 1.0f / (1.0f + expf(-ov));
        float cc = sf * ldin(c0, n * 128 + r, isbf) + si * tanhf(gv);
        hnl[a][r] = so * tanhf(cc);
    }
    __syncthreads();
    {   // output projection, f32 (precision-matched to prior kernel)
        const int jj = tid & 127, a2 = tid >> 7;
        if (jj < 120) {
            const int ch = jj / 20, wc = jj - ch * 20;
#pragma unroll
            for (int ai = 0; ai < 2; ++ai) {
                const int a = a2 + ai * 2, n = n0 + a;
                float acc2 = ldin(bout, jj, isbf);
                for (int r = 0; r < 128; r += 4) {
                    float4 hq = *(const float4*)&hnl[a][r];
                    acc2 = fmaf(hq.x, ws[F_WOUT + (r + 0) * 128 + jj], acc2);
                    acc2 = fmaf(hq.y, ws[F_WOUT + (r + 1) * 128 + jj], acc2);
                    acc2 = fmaf(hq.z, ws[F_WOUT + (r + 2) * 128 + jj], acc2);
                    acc2 = fmaf(hq.w, ws[F_WOUT + (r + 3) * 128 + jj], acc2);
                }
                out[ch * 20480 + n * 20 + wc] = acc2;   // f32, [6][1024][20]
            }
        }
    }
}

extern "C" void kernel_launch(void* const* d_in, const int* in_sizes, int n_in,
                              void* d_out, int out_size, void* d_ws, size_t ws_size,
                              hipStream_t stream) {
    const void* xoff  = d_in[0];
    const void* xabs  = d_in[1];
    const void* h0    = d_in[2];
    const void* c0    = d_in[3];
    const void* W_emb = d_in[4];
    const void* b_emb = d_in[5];
    const void* W_soc = d_in[6];
    const void* b_soc = d_in[7];
    const void* W_ih  = d_in[8];
    const void* W_hh  = d_in[9];
    const void* b_ih  = d_in[10];
    const void* b_hh  = d_in[11];
    const void* W_out = d_in[12];
    const void* b_out = d_in[13];
    float* ws = (float*)d_ws;
    float* out = (float*)d_out;

    fused1_kernel<<<840, 256, 0, stream>>>(xabs, h0, W_soc, W_ih, W_hh, W_out, ws);
    fused2_kernel<<<256, 256, 0, stream>>>(xoff, h0, c0, W_emb, b_emb, b_soc,
                                           b_ih, b_hh, b_out, W_ih, ws, out);
}